// Round 4
// baseline (807.664 us; speedup 1.0000x reference)
//
#include <hip/hip_runtime.h>
#include <hip/hip_bf16.h>

typedef __hip_bfloat16 bf16;

constexpr int cN = 128, cC = 64, cT = 64, cV = 25, cK = 3, cMID = 64, cKM = 192, cTV = 1600;
constexpr float cEPS = 1e-5f;

// All intermediates live in the .so's device image (BSS): zero d_ws dependency.
// Every buffer is fully rewritten before being read on every call -> replay-safe.
__device__ float g_tmp[cN * cC * cV];          // 0.82 MB
__device__ float g_x1 [cN * cKM * cV];         // 2.46 MB
__device__ float g_x2 [cN * cKM * cV];         // 2.46 MB
__device__ float g_ada[cN * cK * cV * cV];     // 0.96 MB
__device__ bf16  g_pre[(size_t)cN * cKM * cTV];// 78.6 MB  relu(bn(W_pre@x))
__device__ bf16  g_y  [(size_t)cN * cKM * cTV];// 78.6 MB  pre_x @ Adyn

__device__ __forceinline__ float b2f(bf16 v){ return __bfloat162float(v); }
__device__ __forceinline__ bf16  f2b(float v){ return __float2bfloat16(v); }

// ---------------------------------------------------------------------------
// 1) g_tmp[n,c,v] = mean_t x[n,c,t,v]      grid = N*C, block = 64
// ---------------------------------------------------------------------------
__global__ void gm_tmp(const float* __restrict__ x){
  int b = blockIdx.x;            // n*cC + c
  int l = threadIdx.x;
  if (l >= cV) return;
  const float* p = x + (size_t)b * cTV + l;
  float s = 0.f;
  #pragma unroll
  for (int t = 0; t < cT; ++t) s += p[t * cV];
  g_tmp[b * cV + l] = s * (1.f / cT);
}

// ---------------------------------------------------------------------------
// 2) g_x1[n,o,v] = sum_c W1[o,c]*g_tmp[n,c,v] + b1[o]   (same for g_x2)
//    grid = N*4 (o-groups of 48), block = 256.  LDS = 30.9 KB
// ---------------------------------------------------------------------------
__global__ void gm_x1x2(const float* __restrict__ W1, const float* __restrict__ b1,
                        const float* __restrict__ W2, const float* __restrict__ b2){
  __shared__ float tl[cC * cV];
  __shared__ float w1[48 * cC];
  __shared__ float w2[48 * cC];
  int n = blockIdx.x >> 2, og = blockIdx.x & 3;
  int tid = threadIdx.x;
  int obase = og * 48;
  for (int i = tid; i < cC * cV; i += 256) tl[i] = g_tmp[n * cC * cV + i];
  for (int i = tid; i < 48 * cC; i += 256){
    w1[i] = W1[obase * cC + i];
    w2[i] = W2[obase * cC + i];
  }
  __syncthreads();
  for (int idx = tid; idx < 48 * cV; idx += 256){
    int j = idx / cV, v = idx % cV;
    int o = obase + j;
    float s1 = b1[o], s2 = b2[o];
    #pragma unroll
    for (int c = 0; c < cC; ++c){
      float t = tl[c * cV + v];
      s1 += w1[j * cC + c] * t;
      s2 += w2[j * cC + c] * t;
    }
    g_x1[((size_t)n * cKM + o) * cV + v] = s1;
    g_x2[((size_t)n * cKM + o) * cV + v] = s2;
  }
}

// ---------------------------------------------------------------------------
// 3) g_ada[n,k,v,w] = softmax_v( sum_c x1[n,k,c,v]*x2[n,k,c,w] ) * beta[0]
//    grid = N*K, block = 128.  LDS = 15.3 KB
// ---------------------------------------------------------------------------
__global__ void gm_ada(const float* __restrict__ beta){
  __shared__ float a1[cMID * cV];
  __shared__ float a2[cMID * cV];
  __shared__ float al[cV * cV];
  int b = blockIdx.x; int n = b / cK, k = b % cK;
  int tid = threadIdx.x;
  const float* p1 = g_x1 + ((size_t)n * cKM + k * cMID) * cV;
  const float* p2 = g_x2 + ((size_t)n * cKM + k * cMID) * cV;
  for (int i = tid; i < cMID * cV; i += 128){ a1[i] = p1[i]; a2[i] = p2[i]; }
  __syncthreads();
  for (int idx = tid; idx < cV * cV; idx += 128){
    int v = idx / cV, w = idx % cV;
    float s = 0.f;
    #pragma unroll
    for (int c = 0; c < cMID; ++c) s += a1[c * cV + v] * a2[c * cV + w];
    al[idx] = s;
  }
  __syncthreads();
  float b0 = beta[0];
  if (tid < cV){
    int w = tid;
    float m = -1e30f;
    for (int v = 0; v < cV; ++v) m = fmaxf(m, al[v * cV + w]);
    float s = 0.f;
    for (int v = 0; v < cV; ++v) s += expf(al[v * cV + w] - m);
    float inv = b0 / s;
    for (int v = 0; v < cV; ++v)
      g_ada[(size_t)b * cV * cV + v * cV + w] = expf(al[v * cV + w] - m) * inv;
  }
}

// ---------------------------------------------------------------------------
// 4) g_pre[n,o,t,v] = relu(bn_pre(W_pre@x + b_pre))  -> bf16
//    grid = N*25 (col tiles of 64 over T*V), block = 256 (4 og x 64 col,
//    48 o's per thread).  C chunked by 32: LDS = 8 + 24 + 1.5 = 33.5 KB
// ---------------------------------------------------------------------------
__global__ void gm_pre(const float* __restrict__ x, const float* __restrict__ Wp,
                       const float* __restrict__ bp, const float* __restrict__ bnp){
  __shared__ float xl[32][64];
  __shared__ float wl[cKM][32];
  __shared__ float sc[cKM], sh[cKM];
  int bid = blockIdx.x; int n = bid / 25, tile = bid % 25;
  int colb = tile * 64, tid = threadIdx.x;
  if (tid < cKM){
    float g = bnp[tid], bb = bnp[cKM + tid], m = bnp[2 * cKM + tid], vv = bnp[3 * cKM + tid];
    float s = g * rsqrtf(vv + cEPS);
    sc[tid] = s;
    sh[tid] = bb - m * s + bp[tid] * s;
  }
  int col = tid & 63, og = tid >> 6;
  float acc[48];
  #pragma unroll
  for (int j = 0; j < 48; ++j) acc[j] = 0.f;
  for (int cc = 0; cc < cC; cc += 32){
    __syncthreads();   // first iter also covers sc/sh init; later protects reuse
    for (int i = tid; i < 32 * 64; i += 256){
      int r = i >> 6, c2 = i & 63;
      xl[r][c2] = x[((size_t)n * cC + cc + r) * cTV + colb + c2];
    }
    for (int i = tid; i < cKM * 32; i += 256){
      int o = i >> 5, c2 = i & 31;
      wl[o][c2] = Wp[o * cC + cc + c2];
    }
    __syncthreads();
    float zr[32];
    #pragma unroll
    for (int c2 = 0; c2 < 32; ++c2) zr[c2] = xl[c2][col];
    #pragma unroll
    for (int j = 0; j < 48; ++j){
      int o = og * 48 + j;
      float s = acc[j];
      #pragma unroll
      for (int c2 = 0; c2 < 32; ++c2) s += wl[o][c2] * zr[c2];
      acc[j] = s;
    }
  }
  #pragma unroll
  for (int j = 0; j < 48; ++j){
    int o = og * 48 + j;
    float r = fmaxf(acc[j] * sc[o] + sh[o], 0.f);
    g_pre[((size_t)n * cKM + o) * cTV + colb + col] = f2b(r);
  }
}

// ---------------------------------------------------------------------------
// 5) g_y[n,o,t,w] = sum_v g_pre[n,o,t,v] * Adyn[n,o,v,w]
//    Adyn = tanh(x1[v]-x2[w])*alpha0 + A[k,v,w] + ada[n,k,v,w]
//    grid = N*KM, block = 128.  LDS = 9.1 KB
// ---------------------------------------------------------------------------
__global__ void gm_y(const float* __restrict__ A, const float* __restrict__ alpha){
  __shared__ float Ad[cV * cV];
  __shared__ float px[cT * cV];
  __shared__ float r1[cV], r2[cV];
  int bid = blockIdx.x; int n = bid / cKM, r = bid % cKM; int k = r / cMID;
  int tid = threadIdx.x;
  if (tid < cV){
    r1[tid] = g_x1[((size_t)n * cKM + r) * cV + tid];
    r2[tid] = g_x2[((size_t)n * cKM + r) * cV + tid];
  }
  __syncthreads();
  float a0 = alpha[0];
  for (int idx = tid; idx < cV * cV; idx += 128){
    int v = idx / cV, w = idx % cV;
    Ad[idx] = tanhf(r1[v] - r2[w]) * a0 + A[k * cV * cV + idx]
            + g_ada[((size_t)n * cK + k) * cV * cV + idx];
  }
  const bf16* pp = g_pre + ((size_t)n * cKM + r) * cTV;
  for (int i = tid; i < cTV; i += 128) px[i] = b2f(pp[i]);
  __syncthreads();
  bf16* yp = g_y + ((size_t)n * cKM + r) * cTV;
  for (int idx = tid; idx < cTV; idx += 128){
    int t = idx / cV, w = idx % cV;
    float s = 0.f;
    #pragma unroll
    for (int v = 0; v < cV; ++v) s += px[t * cV + v] * Ad[v * cV + w];
    yp[idx] = f2b(s);
  }
}

// ---------------------------------------------------------------------------
// 6) out[n,o,t,v] = relu( bn_post(W_post@y + b_post) + bn_down(W_down@x + b_down) )
//    Fused GEMM: Wcat (192x256, bn-scale folded) @ Z=[y;x] (256x1600) per n.
//    OUTPUT IS FLOAT32.  K chunked by 32: LDS = 8 + 24 + 2.25 = 34.3 KB
//    grid = N*25, block = 256 (4 og x 64 col, 48 o's per thread)
// ---------------------------------------------------------------------------
__global__ void gm_out(const float* __restrict__ x,
                       const float* __restrict__ Wpost, const float* __restrict__ bpost,
                       const float* __restrict__ bnpost,
                       const float* __restrict__ Wdown, const float* __restrict__ bdown,
                       const float* __restrict__ bndown,
                       float* __restrict__ out){
  __shared__ float zl[32][64];
  __shared__ float wl[cKM][32];
  __shared__ float cterm[cKM], scP[cKM], scD[cKM];
  int bid = blockIdx.x; int n = bid / 25, tile = bid % 25;
  int colb = tile * 64, tid = threadIdx.x;
  if (tid < cKM){
    int o = tid;
    float gP = bnpost[o], bP = bnpost[cKM + o], mP = bnpost[2 * cKM + o], vP = bnpost[3 * cKM + o];
    float sP = gP * rsqrtf(vP + cEPS);
    float gD = bndown[o], bD = bndown[cKM + o], mD = bndown[2 * cKM + o], vD = bndown[3 * cKM + o];
    float sD = gD * rsqrtf(vD + cEPS);
    scP[o] = sP; scD[o] = sD;
    cterm[o] = bpost[o] * sP + (bP - mP * sP) + bdown[o] * sD + (bD - mD * sD);
  }
  int col = tid & 63, og = tid >> 6;
  float acc[48];
  #pragma unroll
  for (int j = 0; j < 48; ++j) acc[j] = 0.f;
  for (int kk = 0; kk < 256; kk += 32){
    __syncthreads();   // first iter: covers sc/cterm init; later: protects zl/wl reuse
    for (int i = tid; i < 32 * 64; i += 256){
      int rr = i >> 6, cc = i & 63;
      int grow = kk + rr;
      float z;
      if (grow < cKM) z = b2f(g_y[((size_t)n * cKM + grow) * cTV + colb + cc]);
      else            z = x[((size_t)n * cC + (grow - cKM)) * cTV + colb + cc];
      zl[rr][cc] = z;
    }
    for (int i = tid; i < cKM * 32; i += 256){
      int o = i >> 5, k2 = i & 31;
      int gk = kk + k2;
      float wv;
      if (gk < cKM) wv = Wpost[o * cKM + gk] * scP[o];
      else          wv = Wdown[o * cC + (gk - cKM)] * scD[o];
      wl[o][k2] = wv;
    }
    __syncthreads();
    float zr[32];
    #pragma unroll
    for (int k2 = 0; k2 < 32; ++k2) zr[k2] = zl[k2][col];
    #pragma unroll
    for (int j = 0; j < 48; ++j){
      int o = og * 48 + j;
      float s = acc[j];
      #pragma unroll
      for (int k2 = 0; k2 < 32; ++k2) s += wl[o][k2] * zr[k2];
      acc[j] = s;
    }
  }
  #pragma unroll
  for (int j = 0; j < 48; ++j){
    int o = og * 48 + j;
    out[((size_t)n * cKM + o) * cTV + colb + col] = fmaxf(acc[j] + cterm[o], 0.f);
  }
}

// ---------------------------------------------------------------------------
extern "C" void kernel_launch(void* const* d_in, const int* in_sizes, int n_in,
                              void* d_out, int out_size, void* d_ws, size_t ws_size,
                              hipStream_t stream){
  (void)in_sizes; (void)n_in; (void)out_size; (void)d_ws; (void)ws_size;
  const float* x      = (const float*)d_in[0];
  const float* A      = (const float*)d_in[1];
  const float* alpha  = (const float*)d_in[2];
  const float* beta   = (const float*)d_in[3];
  const float* W_pre  = (const float*)d_in[4];
  const float* b_pre  = (const float*)d_in[5];
  const float* bn_pre = (const float*)d_in[6];
  const float* W1     = (const float*)d_in[7];
  const float* b1     = (const float*)d_in[8];
  const float* W2     = (const float*)d_in[9];
  const float* b2     = (const float*)d_in[10];
  const float* W_post = (const float*)d_in[11];
  const float* b_post = (const float*)d_in[12];
  const float* bn_post= (const float*)d_in[13];
  const float* W_down = (const float*)d_in[14];
  const float* b_down = (const float*)d_in[15];
  const float* bn_down= (const float*)d_in[16];
  float* out = (float*)d_out;   // reference output dtype is float32

  gm_tmp  <<<cN * cC,   64, 0, stream>>>(x);
  gm_x1x2 <<<cN * 4,   256, 0, stream>>>(W1, b1, W2, b2);
  gm_ada  <<<cN * cK,  128, 0, stream>>>(beta);
  gm_pre  <<<cN * 25,  256, 0, stream>>>(x, W_pre, b_pre, bn_pre);
  gm_y    <<<cN * cKM, 128, 0, stream>>>(A, alpha);
  gm_out  <<<cN * 25,  256, 0, stream>>>(x, W_post, b_post, bn_post,
                                         W_down, b_down, bn_down, out);
}

// Round 5
// 332.350 us; speedup vs baseline: 2.4302x; 2.4302x over previous
//
#include <hip/hip_runtime.h>
#include <hip/hip_bf16.h>

typedef __hip_bfloat16 bf16;
typedef __attribute__((ext_vector_type(8))) short s16x8;
typedef __attribute__((ext_vector_type(4))) float f32x4;

constexpr int cN = 128, cC = 64, cT = 64, cV = 25, cK = 3, cMID = 64, cKM = 192, cTV = 1600;
constexpr float cEPS = 1e-5f;

// All intermediates in BSS: zero d_ws dependency; fully rewritten each call.
__device__ float g_tmp[cN * cC * cV];
__device__ float g_x1 [cN * cKM * cV];
__device__ float g_x2 [cN * cKM * cV];
__device__ float g_ada[cN * cK * cV * cV];
__device__ bf16  g_pre[(size_t)cN * cKM * cTV];   // 78.6 MB
__device__ bf16  g_y  [(size_t)cN * cKM * cTV];   // 78.6 MB
// Folded weights (bn scale/shift + bias absorbed), built by k_fold each call:
__device__ bf16  g_Wpre [cKM * cC];    // W_pre * scPre        [192][64]
__device__ float g_bpre [cKM];         // bias+shift for pre
__device__ bf16  g_Wcat [cKM * 256];   // [Wpost*scP | Wdown*scD]  [192][256]
__device__ float g_cterm[cKM];         // bias+shift for out

__device__ __forceinline__ float b2f(bf16 v){ return __bfloat162float(v); }
__device__ __forceinline__ bf16  f2b(float v){ return __float2bfloat16(v); }

// ---------------------------------------------------------------------------
// 0) fold bn into weights/biases, cast weights to bf16.  1 block, 256 thr.
// ---------------------------------------------------------------------------
__global__ void k_fold(const float* __restrict__ Wpre, const float* __restrict__ bpre,
                       const float* __restrict__ bnpre,
                       const float* __restrict__ Wpost, const float* __restrict__ bpost,
                       const float* __restrict__ bnpost,
                       const float* __restrict__ Wdown, const float* __restrict__ bdown,
                       const float* __restrict__ bndown){
  __shared__ float sPre[cKM], sPost[cKM], sDown[cKM];
  int tid = threadIdx.x;
  if (tid < cKM){
    float sp = bnpre[tid] * rsqrtf(bnpre[3*cKM+tid] + cEPS);
    sPre[tid] = sp;
    g_bpre[tid] = bpre[tid]*sp + bnpre[cKM+tid] - bnpre[2*cKM+tid]*sp;
    float sP = bnpost[tid] * rsqrtf(bnpost[3*cKM+tid] + cEPS);
    float sD = bndown[tid] * rsqrtf(bndown[3*cKM+tid] + cEPS);
    sPost[tid] = sP; sDown[tid] = sD;
    g_cterm[tid] = bpost[tid]*sP + bnpost[cKM+tid] - bnpost[2*cKM+tid]*sP
                 + bdown[tid]*sD + bndown[cKM+tid] - bndown[2*cKM+tid]*sD;
  }
  __syncthreads();
  for (int idx = tid; idx < cKM*cC; idx += 256){
    int o = idx >> 6;
    g_Wpre[idx] = f2b(Wpre[idx] * sPre[o]);
  }
  for (int idx = tid; idx < cKM*256; idx += 256){
    int o = idx >> 8, k = idx & 255;
    float w = (k < cKM) ? Wpost[o*cKM + k] * sPost[o]
                        : Wdown[o*cC + (k - cKM)] * sDown[o];
    g_Wcat[idx] = f2b(w);
  }
}

// ---------------------------------------------------------------------------
// 1) g_tmp[n,c,v] = mean_t x[n,c,t,v]
// ---------------------------------------------------------------------------
__global__ void gm_tmp(const float* __restrict__ x){
  int b = blockIdx.x;
  int l = threadIdx.x;
  if (l >= cV) return;
  const float* p = x + (size_t)b * cTV + l;
  float s = 0.f;
  #pragma unroll
  for (int t = 0; t < cT; ++t) s += p[t * cV];
  g_tmp[b * cV + l] = s * (1.f / cT);
}

// ---------------------------------------------------------------------------
// 2) x1/x2 1x1 conv on mean
// ---------------------------------------------------------------------------
__global__ void gm_x1x2(const float* __restrict__ W1, const float* __restrict__ b1,
                        const float* __restrict__ W2, const float* __restrict__ b2){
  __shared__ float tl[cC * cV];
  __shared__ float w1[48 * cC];
  __shared__ float w2[48 * cC];
  int n = blockIdx.x >> 2, og = blockIdx.x & 3;
  int tid = threadIdx.x;
  int obase = og * 48;
  for (int i = tid; i < cC * cV; i += 256) tl[i] = g_tmp[n * cC * cV + i];
  for (int i = tid; i < 48 * cC; i += 256){
    w1[i] = W1[obase * cC + i];
    w2[i] = W2[obase * cC + i];
  }
  __syncthreads();
  for (int idx = tid; idx < 48 * cV; idx += 256){
    int j = idx / cV, v = idx % cV;
    int o = obase + j;
    float s1 = b1[o], s2 = b2[o];
    #pragma unroll
    for (int c = 0; c < cC; ++c){
      float t = tl[c * cV + v];
      s1 += w1[j * cC + c] * t;
      s2 += w2[j * cC + c] * t;
    }
    g_x1[((size_t)n * cKM + o) * cV + v] = s1;
    g_x2[((size_t)n * cKM + o) * cV + v] = s2;
  }
}

// ---------------------------------------------------------------------------
// 3) ada softmax
// ---------------------------------------------------------------------------
__global__ void gm_ada(const float* __restrict__ beta){
  __shared__ float a1[cMID * cV];
  __shared__ float a2[cMID * cV];
  __shared__ float al[cV * cV];
  int b = blockIdx.x; int n = b / cK, k = b % cK;
  int tid = threadIdx.x;
  const float* p1 = g_x1 + ((size_t)n * cKM + k * cMID) * cV;
  const float* p2 = g_x2 + ((size_t)n * cKM + k * cMID) * cV;
  for (int i = tid; i < cMID * cV; i += 128){ a1[i] = p1[i]; a2[i] = p2[i]; }
  __syncthreads();
  for (int idx = tid; idx < cV * cV; idx += 128){
    int v = idx / cV, w = idx % cV;
    float s = 0.f;
    #pragma unroll
    for (int c = 0; c < cMID; ++c) s += a1[c * cV + v] * a2[c * cV + w];
    al[idx] = s;
  }
  __syncthreads();
  float b0 = beta[0];
  if (tid < cV){
    int w = tid;
    float m = -1e30f;
    for (int v = 0; v < cV; ++v) m = fmaxf(m, al[v * cV + w]);
    float s = 0.f;
    for (int v = 0; v < cV; ++v) s += expf(al[v * cV + w] - m);
    float inv = b0 / s;
    for (int v = 0; v < cV; ++v)
      g_ada[(size_t)b * cV * cV + v * cV + w] = expf(al[v * cV + w] - m) * inv;
  }
}

// ---------------------------------------------------------------------------
// 4+6) MFMA GEMM: C[192 x 64cols] = W[192 x K] @ Z[K x 64cols] per (n, coltile)
//   MODE 0: K=64,  W=g_Wpre,  Z=x (f32->bf16),     out = g_pre (bf16, relu)
//   MODE 1: K=256, W=g_Wcat,  Z=[g_y; x],          out = d_out (f32, relu)
//   block = 256 thr = 4 waves; wave w owns rows 48w..48w+47 (3 m-frags x 4 n-frags)
//   v_mfma_f32_16x16x32_bf16:  A[m=l&15][k=8*(l>>4)+j], B[k][n=l&15],
//                              D[m=4*(l>>4)+q][n=l&15]   (C/D per learn_hip m89)
//   LDS: Wt[192][56] + Zt[64][56] (ushort, 112B rows: 16B-aligned b128) + cb
// ---------------------------------------------------------------------------
template<int MODE>
__global__ __launch_bounds__(256) void gm_mm(const float* __restrict__ x,
                                             float* __restrict__ outf){
  constexpr int KTOT = MODE ? 256 : 64;
  constexpr int LDW = 56;
  __shared__ ushort Wt[cKM * LDW];
  __shared__ ushort Zt[64 * LDW];
  __shared__ float cb[cKM];
  int n = blockIdx.x / 25, tile = blockIdx.x % 25;
  int colb = tile * 64;
  int tid = threadIdx.x;
  int lane = tid & 63, wv = tid >> 6;
  int g = lane >> 4, l15 = lane & 15;
  int zr = tid >> 3, cj = (tid & 7) * 8;          // Z staging: row, col-group

  if (tid < cKM) cb[tid] = MODE ? g_cterm[tid] : g_bpre[tid];

  f32x4 acc[3][4];
  #pragma unroll
  for (int a = 0; a < 3; ++a)
    #pragma unroll
    for (int b = 0; b < 4; ++b) acc[a][b] = (f32x4){0.f,0.f,0.f,0.f};

  const ushort* Wsrc = (const ushort*)(MODE ? g_Wcat : g_Wpre);

  for (int kb = 0; kb < KTOT; kb += 32){
    __syncthreads();                              // also covers cb on first iter
    // ---- stage W tile [192][32] (row-major, k-fast) ----
    #pragma unroll
    for (int p = 0; p < 3; ++p){
      int c = tid + p * 256;                      // 768 chunks of 8 bf16
      int o = c >> 2, kg = (c & 3) * 8;
      uint4 wv4 = *(const uint4*)(Wsrc + o * KTOT + kb + kg);
      *(uint4*)&Wt[o * LDW + kg] = wv4;
    }
    // ---- stage Z tile transposed: Zt[col][k] ----
    int kt = kb + zr;
    union { uint4 v; ushort u[8]; } zz;
    if (MODE == 1 && kt < cKM){
      zz.v = *(const uint4*)((const ushort*)g_y + ((size_t)n*cKM + kt)*cTV + colb + cj);
    } else {
      int cx = MODE ? (kt - cKM) : kt;
      const float* src = x + ((size_t)n*cC + cx)*cTV + colb + cj;
      float4 f0 = *(const float4*)src;
      float4 f1 = *(const float4*)(src + 4);
      zz.u[0] = __builtin_bit_cast(ushort, f2b(f0.x));
      zz.u[1] = __builtin_bit_cast(ushort, f2b(f0.y));
      zz.u[2] = __builtin_bit_cast(ushort, f2b(f0.z));
      zz.u[3] = __builtin_bit_cast(ushort, f2b(f0.w));
      zz.u[4] = __builtin_bit_cast(ushort, f2b(f1.x));
      zz.u[5] = __builtin_bit_cast(ushort, f2b(f1.y));
      zz.u[6] = __builtin_bit_cast(ushort, f2b(f1.z));
      zz.u[7] = __builtin_bit_cast(ushort, f2b(f1.w));
    }
    #pragma unroll
    for (int j = 0; j < 8; ++j) Zt[(cj + j) * LDW + zr] = zz.u[j];
    __syncthreads();
    // ---- 12 MFMAs ----
    s16x8 av[3], bv[4];
    #pragma unroll
    for (int mf = 0; mf < 3; ++mf)
      av[mf] = *(const s16x8*)&Wt[(48*wv + 16*mf + l15) * LDW + 8*g];
    #pragma unroll
    for (int nf = 0; nf < 4; ++nf)
      bv[nf] = *(const s16x8*)&Zt[(16*nf + l15) * LDW + 8*g];
    #pragma unroll
    for (int mf = 0; mf < 3; ++mf)
      #pragma unroll
      for (int nf = 0; nf < 4; ++nf)
        acc[mf][nf] = __builtin_amdgcn_mfma_f32_16x16x32_bf16(av[mf], bv[nf], acc[mf][nf], 0, 0, 0);
  }
  // ---- epilogue: bias + relu ----
  #pragma unroll
  for (int mf = 0; mf < 3; ++mf)
    #pragma unroll
    for (int nf = 0; nf < 4; ++nf)
      #pragma unroll
      for (int q = 0; q < 4; ++q){
        int o = 48*wv + 16*mf + 4*g + q;
        int col = colb + 16*nf + l15;
        float v = fmaxf(acc[mf][nf][q] + cb[o], 0.f);
        if (MODE) outf[((size_t)n*cKM + o)*cTV + col] = v;
        else      g_pre[((size_t)n*cKM + o)*cTV + col] = f2b(v);
      }
}

// ---------------------------------------------------------------------------
// 5) g_y = pre_x @ Adyn  (per n, channel)
// ---------------------------------------------------------------------------
__global__ void gm_y(const float* __restrict__ A, const float* __restrict__ alpha){
  __shared__ float Ad[cV * cV];
  __shared__ float px[cT * cV];
  __shared__ float r1[cV], r2[cV];
  int bid = blockIdx.x; int n = bid / cKM, r = bid % cKM; int k = r / cMID;
  int tid = threadIdx.x;
  if (tid < cV){
    r1[tid] = g_x1[((size_t)n * cKM + r) * cV + tid];
    r2[tid] = g_x2[((size_t)n * cKM + r) * cV + tid];
  }
  __syncthreads();
  float a0 = alpha[0];
  for (int idx = tid; idx < cV * cV; idx += 128){
    int v = idx / cV, w = idx % cV;
    Ad[idx] = tanhf(r1[v] - r2[w]) * a0 + A[k * cV * cV + idx]
            + g_ada[((size_t)n * cK + k) * cV * cV + idx];
  }
  const bf16* pp = g_pre + ((size_t)n * cKM + r) * cTV;
  for (int i = tid; i < cTV; i += 128) px[i] = b2f(pp[i]);
  __syncthreads();
  bf16* yp = g_y + ((size_t)n * cKM + r) * cTV;
  for (int idx = tid; idx < cTV; idx += 128){
    int t = idx / cV, w = idx % cV;
    float s = 0.f;
    #pragma unroll
    for (int v = 0; v < cV; ++v) s += px[t * cV + v] * Ad[v * cV + w];
    yp[idx] = f2b(s);
  }
}

// ---------------------------------------------------------------------------
extern "C" void kernel_launch(void* const* d_in, const int* in_sizes, int n_in,
                              void* d_out, int out_size, void* d_ws, size_t ws_size,
                              hipStream_t stream){
  (void)in_sizes; (void)n_in; (void)out_size; (void)d_ws; (void)ws_size;
  const float* x      = (const float*)d_in[0];
  const float* A      = (const float*)d_in[1];
  const float* alpha  = (const float*)d_in[2];
  const float* beta   = (const float*)d_in[3];
  const float* W_pre  = (const float*)d_in[4];
  const float* b_pre  = (const float*)d_in[5];
  const float* bn_pre = (const float*)d_in[6];
  const float* W1     = (const float*)d_in[7];
  const float* b1     = (const float*)d_in[8];
  const float* W2     = (const float*)d_in[9];
  const float* b2     = (const float*)d_in[10];
  const float* W_post = (const float*)d_in[11];
  const float* b_post = (const float*)d_in[12];
  const float* bn_post= (const float*)d_in[13];
  const float* W_down = (const float*)d_in[14];
  const float* b_down = (const float*)d_in[15];
  const float* bn_down= (const float*)d_in[16];
  float* out = (float*)d_out;

  k_fold  <<<1,        256, 0, stream>>>(W_pre, b_pre, bn_pre,
                                         W_post, b_post, bn_post,
                                         W_down, b_down, bn_down);
  gm_tmp  <<<cN * cC,   64, 0, stream>>>(x);
  gm_x1x2 <<<cN * 4,   256, 0, stream>>>(W1, b1, W2, b2);
  gm_ada  <<<cN * cK,  128, 0, stream>>>(beta);
  gm_mm<0><<<cN * 25,  256, 0, stream>>>(x, nullptr);
  gm_y    <<<cN * cKM, 128, 0, stream>>>(A, alpha);
  gm_mm<1><<<cN * 25,  256, 0, stream>>>(x, out);
}

// Round 6
// 320.988 us; speedup vs baseline: 2.5162x; 1.0354x over previous
//
#include <hip/hip_runtime.h>
#include <hip/hip_bf16.h>

typedef __hip_bfloat16 bf16;
typedef __attribute__((ext_vector_type(8))) short s16x8;
typedef __attribute__((ext_vector_type(4))) float f32x4;

constexpr int cN = 128, cC = 64, cT = 64, cV = 25, cK = 3, cMID = 64, cKM = 192, cTV = 1600;
constexpr float cEPS = 1e-5f;

// All intermediates in BSS: zero d_ws dependency; fully rewritten each call.
__device__ float g_tmp[cN * cC * cV];
__device__ float g_x1 [cN * cKM * cV];
__device__ float g_x2 [cN * cKM * cV];
__device__ float g_ada[cN * cK * cV * cV];
__device__ bf16  g_pre[(size_t)cN * cKM * cTV];   // 78.6 MB
__device__ bf16  g_y  [(size_t)cN * cKM * cTV];   // 78.6 MB
// Folded weights (bn scale/shift + bias absorbed), built by k_fold each call:
__device__ bf16  g_Wpre [cKM * cC];    // W_pre * scPre        [192][64]
__device__ float g_bpre [cKM];         // bias+shift for pre
__device__ bf16  g_Wcat [cKM * 256];   // [Wpost*scP | Wdown*scD]  [192][256]
__device__ float g_cterm[cKM];         // bias+shift for out

__device__ __forceinline__ float b2f(bf16 v){ return __bfloat162float(v); }
__device__ __forceinline__ bf16  f2b(float v){ return __float2bfloat16(v); }

// ---------------------------------------------------------------------------
// 0) fold bn into weights/biases, cast weights to bf16.  1 block, 256 thr.
// ---------------------------------------------------------------------------
__global__ void k_fold(const float* __restrict__ Wpre, const float* __restrict__ bpre,
                       const float* __restrict__ bnpre,
                       const float* __restrict__ Wpost, const float* __restrict__ bpost,
                       const float* __restrict__ bnpost,
                       const float* __restrict__ Wdown, const float* __restrict__ bdown,
                       const float* __restrict__ bndown){
  __shared__ float sPre[cKM], sPost[cKM], sDown[cKM];
  int tid = threadIdx.x;
  if (tid < cKM){
    float sp = bnpre[tid] * rsqrtf(bnpre[3*cKM+tid] + cEPS);
    sPre[tid] = sp;
    g_bpre[tid] = bpre[tid]*sp + bnpre[cKM+tid] - bnpre[2*cKM+tid]*sp;
    float sP = bnpost[tid] * rsqrtf(bnpost[3*cKM+tid] + cEPS);
    float sD = bndown[tid] * rsqrtf(bndown[3*cKM+tid] + cEPS);
    sPost[tid] = sP; sDown[tid] = sD;
    g_cterm[tid] = bpost[tid]*sP + bnpost[cKM+tid] - bnpost[2*cKM+tid]*sP
                 + bdown[tid]*sD + bndown[cKM+tid] - bndown[2*cKM+tid]*sD;
  }
  __syncthreads();
  for (int idx = tid; idx < cKM*cC; idx += 256){
    int o = idx >> 6;
    g_Wpre[idx] = f2b(Wpre[idx] * sPre[o]);
  }
  for (int idx = tid; idx < cKM*256; idx += 256){
    int o = idx >> 8, k = idx & 255;
    float w = (k < cKM) ? Wpost[o*cKM + k] * sPost[o]
                        : Wdown[o*cC + (k - cKM)] * sDown[o];
    g_Wcat[idx] = f2b(w);
  }
}

// ---------------------------------------------------------------------------
// 1) g_tmp[n,c,v] = mean_t x[n,c,t,v]
// ---------------------------------------------------------------------------
__global__ void gm_tmp(const float* __restrict__ x){
  int b = blockIdx.x;
  int l = threadIdx.x;
  if (l >= cV) return;
  const float* p = x + (size_t)b * cTV + l;
  float s = 0.f;
  #pragma unroll
  for (int t = 0; t < cT; ++t) s += p[t * cV];
  g_tmp[b * cV + l] = s * (1.f / cT);
}

// ---------------------------------------------------------------------------
// 2) x1/x2 1x1 conv on mean
// ---------------------------------------------------------------------------
__global__ void gm_x1x2(const float* __restrict__ W1, const float* __restrict__ b1,
                        const float* __restrict__ W2, const float* __restrict__ b2){
  __shared__ float tl[cC * cV];
  __shared__ float w1[48 * cC];
  __shared__ float w2[48 * cC];
  int n = blockIdx.x >> 2, og = blockIdx.x & 3;
  int tid = threadIdx.x;
  int obase = og * 48;
  for (int i = tid; i < cC * cV; i += 256) tl[i] = g_tmp[n * cC * cV + i];
  for (int i = tid; i < 48 * cC; i += 256){
    w1[i] = W1[obase * cC + i];
    w2[i] = W2[obase * cC + i];
  }
  __syncthreads();
  for (int idx = tid; idx < 48 * cV; idx += 256){
    int j = idx / cV, v = idx % cV;
    int o = obase + j;
    float s1 = b1[o], s2 = b2[o];
    #pragma unroll
    for (int c = 0; c < cC; ++c){
      float t = tl[c * cV + v];
      s1 += w1[j * cC + c] * t;
      s2 += w2[j * cC + c] * t;
    }
    g_x1[((size_t)n * cKM + o) * cV + v] = s1;
    g_x2[((size_t)n * cKM + o) * cV + v] = s2;
  }
}

// ---------------------------------------------------------------------------
// 3) ada softmax
// ---------------------------------------------------------------------------
__global__ void gm_ada(const float* __restrict__ beta){
  __shared__ float a1[cMID * cV];
  __shared__ float a2[cMID * cV];
  __shared__ float al[cV * cV];
  int b = blockIdx.x; int n = b / cK, k = b % cK;
  int tid = threadIdx.x;
  const float* p1 = g_x1 + ((size_t)n * cKM + k * cMID) * cV;
  const float* p2 = g_x2 + ((size_t)n * cKM + k * cMID) * cV;
  for (int i = tid; i < cMID * cV; i += 128){ a1[i] = p1[i]; a2[i] = p2[i]; }
  __syncthreads();
  for (int idx = tid; idx < cV * cV; idx += 128){
    int v = idx / cV, w = idx % cV;
    float s = 0.f;
    #pragma unroll
    for (int c = 0; c < cMID; ++c) s += a1[c * cV + v] * a2[c * cV + w];
    al[idx] = s;
  }
  __syncthreads();
  float b0 = beta[0];
  if (tid < cV){
    int w = tid;
    float m = -1e30f;
    for (int v = 0; v < cV; ++v) m = fmaxf(m, al[v * cV + w]);
    float s = 0.f;
    for (int v = 0; v < cV; ++v) s += expf(al[v * cV + w] - m);
    float inv = b0 / s;
    for (int v = 0; v < cV; ++v)
      g_ada[(size_t)b * cV * cV + v * cV + w] = expf(al[v * cV + w] - m) * inv;
  }
}

// ---------------------------------------------------------------------------
// 4+6) MFMA GEMM: C[192 x 64cols] = W[192 x K] @ Z[K x 64cols] per (n, coltile)
//   MODE 0: K=64,  W=g_Wpre,  Z=x (f32->bf16),     out = g_pre (bf16, relu)
//   MODE 1: K=256, W=g_Wcat,  Z=[g_y; x],          out = d_out (f32, relu)
// ---------------------------------------------------------------------------
template<int MODE>
__global__ __launch_bounds__(256) void gm_mm(const float* __restrict__ x,
                                             float* __restrict__ outf){
  constexpr int KTOT = MODE ? 256 : 64;
  constexpr int LDW = 56;
  __shared__ ushort Wt[cKM * LDW];
  __shared__ ushort Zt[64 * LDW];
  __shared__ float cb[cKM];
  int n = blockIdx.x / 25, tile = blockIdx.x % 25;
  int colb = tile * 64;
  int tid = threadIdx.x;
  int lane = tid & 63, wv = tid >> 6;
  int g = lane >> 4, l15 = lane & 15;
  int zr = tid >> 3, cj = (tid & 7) * 8;          // Z staging: row, col-group

  if (tid < cKM) cb[tid] = MODE ? g_cterm[tid] : g_bpre[tid];

  f32x4 acc[3][4];
  #pragma unroll
  for (int a = 0; a < 3; ++a)
    #pragma unroll
    for (int b = 0; b < 4; ++b) acc[a][b] = (f32x4){0.f,0.f,0.f,0.f};

  const ushort* Wsrc = (const ushort*)(MODE ? g_Wcat : g_Wpre);

  for (int kb = 0; kb < KTOT; kb += 32){
    __syncthreads();                              // also covers cb on first iter
    // ---- stage W tile [192][32] (row-major, k-fast) ----
    #pragma unroll
    for (int p = 0; p < 3; ++p){
      int c = tid + p * 256;                      // 768 chunks of 8 bf16
      int o = c >> 2, kg = (c & 3) * 8;
      uint4 wv4 = *(const uint4*)(Wsrc + o * KTOT + kb + kg);
      *(uint4*)&Wt[o * LDW + kg] = wv4;
    }
    // ---- stage Z tile transposed: Zt[col][k] ----
    int kt = kb + zr;
    union { uint4 v; ushort u[8]; } zz;
    if (MODE == 1 && kt < cKM){
      zz.v = *(const uint4*)((const ushort*)g_y + ((size_t)n*cKM + kt)*cTV + colb + cj);
    } else {
      int cx = MODE ? (kt - cKM) : kt;
      const float* src = x + ((size_t)n*cC + cx)*cTV + colb + cj;
      float4 f0 = *(const float4*)src;
      float4 f1 = *(const float4*)(src + 4);
      zz.u[0] = __builtin_bit_cast(ushort, f2b(f0.x));
      zz.u[1] = __builtin_bit_cast(ushort, f2b(f0.y));
      zz.u[2] = __builtin_bit_cast(ushort, f2b(f0.z));
      zz.u[3] = __builtin_bit_cast(ushort, f2b(f0.w));
      zz.u[4] = __builtin_bit_cast(ushort, f2b(f1.x));
      zz.u[5] = __builtin_bit_cast(ushort, f2b(f1.y));
      zz.u[6] = __builtin_bit_cast(ushort, f2b(f1.z));
      zz.u[7] = __builtin_bit_cast(ushort, f2b(f1.w));
    }
    #pragma unroll
    for (int j = 0; j < 8; ++j) Zt[(cj + j) * LDW + zr] = zz.u[j];
    __syncthreads();
    // ---- 12 MFMAs ----
    s16x8 av[3], bv[4];
    #pragma unroll
    for (int mf = 0; mf < 3; ++mf)
      av[mf] = *(const s16x8*)&Wt[(48*wv + 16*mf + l15) * LDW + 8*g];
    #pragma unroll
    for (int nf = 0; nf < 4; ++nf)
      bv[nf] = *(const s16x8*)&Zt[(16*nf + l15) * LDW + 8*g];
    #pragma unroll
    for (int mf = 0; mf < 3; ++mf)
      #pragma unroll
      for (int nf = 0; nf < 4; ++nf)
        acc[mf][nf] = __builtin_amdgcn_mfma_f32_16x16x32_bf16(av[mf], bv[nf], acc[mf][nf], 0, 0, 0);
  }
  // ---- epilogue: bias + relu ----
  #pragma unroll
  for (int mf = 0; mf < 3; ++mf)
    #pragma unroll
    for (int nf = 0; nf < 4; ++nf)
      #pragma unroll
      for (int q = 0; q < 4; ++q){
        int o = 48*wv + 16*mf + 4*g + q;
        int col = colb + 16*nf + l15;
        float v = fmaxf(acc[mf][nf][q] + cb[o], 0.f);
        if (MODE) outf[((size_t)n*cKM + o)*cTV + col] = v;
        else      g_pre[((size_t)n*cKM + o)*cTV + col] = f2b(v);
      }
}

// ---------------------------------------------------------------------------
// 5) g_y = pre_x @ Adyn via MFMA.  One wave per (n,r).
//    A = pre_x row-block [64(t) x 25(v)] padded to k=32
//    B = Adyn [25(v) x 25(w)] padded, stored transposed Adt[w][v] (bf16)
//    4 m-frags x 2 n-frags of v_mfma_f32_16x16x32_bf16; cols w>=25 dropped.
//    LDS row stride 56 (112B): zero bank conflicts (validated in gm_mm r4/r5).
// ---------------------------------------------------------------------------
__global__ __launch_bounds__(64) void gm_y_mfma(const float* __restrict__ A,
                                                const float* __restrict__ alpha){
  constexpr int LDW = 56;
  __shared__ ushort Adt[32 * LDW];   // [w][v] bf16, padded with zeros
  __shared__ ushort pxl[64 * LDW];   // [t][v] bf16, padded with zeros
  __shared__ float r1s[cV], r2s[cV];
  int bid = blockIdx.x; int n = bid / cKM, r = bid % cKM; int k = r / cMID;
  int lane = threadIdx.x;
  if (lane < cV){
    r1s[lane] = g_x1[((size_t)n * cKM + r) * cV + lane];
    r2s[lane] = g_x2[((size_t)n * cKM + r) * cV + lane];
  }
  __syncthreads();
  float a0 = alpha[0];
  const float* Ak   = A + k * cV * cV;
  const float* adak = g_ada + ((size_t)n * cK + k) * cV * cV;
  // Adyn -> Adt[w][v], zero-padded to 32x32 region
  for (int idx = lane; idx < 32 * 32; idx += 64){
    int w = idx >> 5, v = idx & 31;
    float val = 0.f;
    if (v < cV && w < cV)
      val = tanhf(r1s[v] - r2s[w]) * a0 + Ak[v * cV + w] + adak[v * cV + w];
    Adt[w * LDW + v] = __builtin_bit_cast(ushort, f2b(val));
  }
  // pre_x row-block -> pxl[t][v], zero-padded
  const ushort* pp = (const ushort*)(g_pre + ((size_t)n * cKM + r) * cTV);
  for (int idx = lane; idx < 64 * 32; idx += 64){
    int t = idx >> 5, v = idx & 31;
    ushort val = 0;
    if (v < cV) val = pp[t * cV + v];
    pxl[t * LDW + v] = val;
  }
  __syncthreads();
  int g = lane >> 4, l15 = lane & 15;
  s16x8 av[4], bv[2];
  #pragma unroll
  for (int mf = 0; mf < 4; ++mf)
    av[mf] = *(const s16x8*)&pxl[(16*mf + l15) * LDW + 8*g];
  #pragma unroll
  for (int nf = 0; nf < 2; ++nf)
    bv[nf] = *(const s16x8*)&Adt[(16*nf + l15) * LDW + 8*g];
  f32x4 acc[4][2];
  #pragma unroll
  for (int mf = 0; mf < 4; ++mf)
    #pragma unroll
    for (int nf = 0; nf < 2; ++nf) acc[mf][nf] = (f32x4){0.f,0.f,0.f,0.f};
  #pragma unroll
  for (int mf = 0; mf < 4; ++mf)
    #pragma unroll
    for (int nf = 0; nf < 2; ++nf)
      acc[mf][nf] = __builtin_amdgcn_mfma_f32_16x16x32_bf16(av[mf], bv[nf], acc[mf][nf], 0, 0, 0);
  // store y[t][w], w < 25
  ushort* yp = (ushort*)(g_y + ((size_t)n * cKM + r) * cTV);
  #pragma unroll
  for (int mf = 0; mf < 4; ++mf)
    #pragma unroll
    for (int nf = 0; nf < 2; ++nf)
      #pragma unroll
      for (int q = 0; q < 4; ++q){
        int t = 16*mf + 4*g + q, w = 16*nf + l15;
        if (w < cV)
          yp[t * cV + w] = __builtin_bit_cast(ushort, f2b(acc[mf][nf][q]));
      }
}

// ---------------------------------------------------------------------------
extern "C" void kernel_launch(void* const* d_in, const int* in_sizes, int n_in,
                              void* d_out, int out_size, void* d_ws, size_t ws_size,
                              hipStream_t stream){
  (void)in_sizes; (void)n_in; (void)out_size; (void)d_ws; (void)ws_size;
  const float* x      = (const float*)d_in[0];
  const float* A      = (const float*)d_in[1];
  const float* alpha  = (const float*)d_in[2];
  const float* beta   = (const float*)d_in[3];
  const float* W_pre  = (const float*)d_in[4];
  const float* b_pre  = (const float*)d_in[5];
  const float* bn_pre = (const float*)d_in[6];
  const float* W1     = (const float*)d_in[7];
  const float* b1     = (const float*)d_in[8];
  const float* W2     = (const float*)d_in[9];
  const float* b2     = (const float*)d_in[10];
  const float* W_post = (const float*)d_in[11];
  const float* b_post = (const float*)d_in[12];
  const float* bn_post= (const float*)d_in[13];
  const float* W_down = (const float*)d_in[14];
  const float* b_down = (const float*)d_in[15];
  const float* bn_down= (const float*)d_in[16];
  float* out = (float*)d_out;

  k_fold  <<<1,         256, 0, stream>>>(W_pre, b_pre, bn_pre,
                                          W_post, b_post, bn_post,
                                          W_down, b_down, bn_down);
  gm_tmp  <<<cN * cC,    64, 0, stream>>>(x);
  gm_x1x2 <<<cN * 4,    256, 0, stream>>>(W1, b1, W2, b2);
  gm_ada  <<<cN * cK,   128, 0, stream>>>(beta);
  gm_mm<0><<<cN * 25,   256, 0, stream>>>(x, nullptr);
  gm_y_mfma<<<cN * cKM,  64, 0, stream>>>(A, alpha);
  gm_mm<1><<<cN * 25,   256, 0, stream>>>(x, out);
}

// Round 7
// 263.410 us; speedup vs baseline: 3.0662x; 1.2186x over previous
//
#include <hip/hip_runtime.h>
#include <hip/hip_bf16.h>

typedef __hip_bfloat16 bf16;
typedef __attribute__((ext_vector_type(8))) short s16x8;
typedef __attribute__((ext_vector_type(4))) float f32x4;

constexpr int cN = 128, cC = 64, cT = 64, cV = 25, cK = 3, cMID = 64, cKM = 192, cTV = 1600;
constexpr float cEPS = 1e-5f;

// All intermediates in BSS: zero d_ws dependency; loader zero-inits once.
__device__ float g_tmp[cN * cC * cV];
__device__ float g_x1 [cN * cKM * cV];
__device__ float g_x2 [cN * cKM * cV];
__device__ float g_ada[cN * cK * cV * cV];
// pre_x in v-PADDED layout [n][o][t][32] (v=25..31 never written; only ever
// multiplied by exact-zero B rows, and BSS is loader-zeroed -> safe).
__device__ ushort g_pre32[(size_t)cN * cKM * cT * 32];   // 100.7 MB
__device__ bf16   g_y  [(size_t)cN * cKM * cTV];         // 78.6 MB (compact)
// Folded weights (bn scale/shift + bias absorbed), built by k_fold each call:
__device__ bf16  g_Wpre [cKM * cC];
__device__ float g_bpre [cKM];
__device__ bf16  g_Wcat [cKM * 256];
__device__ float g_cterm[cKM];

__device__ __forceinline__ float b2f(bf16 v){ return __bfloat162float(v); }
__device__ __forceinline__ bf16  f2b(float v){ return __float2bfloat16(v); }
__device__ __forceinline__ ushort f2bu(float v){ return __builtin_bit_cast(ushort, __float2bfloat16(v)); }

// ---------------------------------------------------------------------------
// 0) fold bn into weights/biases, cast weights to bf16.  1 block, 256 thr.
// ---------------------------------------------------------------------------
__global__ void k_fold(const float* __restrict__ Wpre, const float* __restrict__ bpre,
                       const float* __restrict__ bnpre,
                       const float* __restrict__ Wpost, const float* __restrict__ bpost,
                       const float* __restrict__ bnpost,
                       const float* __restrict__ Wdown, const float* __restrict__ bdown,
                       const float* __restrict__ bndown){
  __shared__ float sPre[cKM], sPost[cKM], sDown[cKM];
  int tid = threadIdx.x;
  if (tid < cKM){
    float sp = bnpre[tid] * rsqrtf(bnpre[3*cKM+tid] + cEPS);
    sPre[tid] = sp;
    g_bpre[tid] = bpre[tid]*sp + bnpre[cKM+tid] - bnpre[2*cKM+tid]*sp;
    float sP = bnpost[tid] * rsqrtf(bnpost[3*cKM+tid] + cEPS);
    float sD = bndown[tid] * rsqrtf(bndown[3*cKM+tid] + cEPS);
    sPost[tid] = sP; sDown[tid] = sD;
    g_cterm[tid] = bpost[tid]*sP + bnpost[cKM+tid] - bnpost[2*cKM+tid]*sP
                 + bdown[tid]*sD + bndown[cKM+tid] - bndown[2*cKM+tid]*sD;
  }
  __syncthreads();
  for (int idx = tid; idx < cKM*cC; idx += 256){
    int o = idx >> 6;
    g_Wpre[idx] = f2b(Wpre[idx] * sPre[o]);
  }
  for (int idx = tid; idx < cKM*256; idx += 256){
    int o = idx >> 8, k = idx & 255;
    float w = (k < cKM) ? Wpost[o*cKM + k] * sPost[o]
                        : Wdown[o*cC + (k - cKM)] * sDown[o];
    g_Wcat[idx] = f2b(w);
  }
}

// ---------------------------------------------------------------------------
// 1) g_tmp[n,c,v] = mean_t x[n,c,t,v]
// ---------------------------------------------------------------------------
__global__ void gm_tmp(const float* __restrict__ x){
  int b = blockIdx.x;
  int l = threadIdx.x;
  if (l >= cV) return;
  const float* p = x + (size_t)b * cTV + l;
  float s = 0.f;
  #pragma unroll
  for (int t = 0; t < cT; ++t) s += p[t * cV];
  g_tmp[b * cV + l] = s * (1.f / cT);
}

// ---------------------------------------------------------------------------
// 2) x1/x2 1x1 conv on mean
// ---------------------------------------------------------------------------
__global__ void gm_x1x2(const float* __restrict__ W1, const float* __restrict__ b1,
                        const float* __restrict__ W2, const float* __restrict__ b2){
  __shared__ float tl[cC * cV];
  __shared__ float w1[48 * cC];
  __shared__ float w2[48 * cC];
  int n = blockIdx.x >> 2, og = blockIdx.x & 3;
  int tid = threadIdx.x;
  int obase = og * 48;
  for (int i = tid; i < cC * cV; i += 256) tl[i] = g_tmp[n * cC * cV + i];
  for (int i = tid; i < 48 * cC; i += 256){
    w1[i] = W1[obase * cC + i];
    w2[i] = W2[obase * cC + i];
  }
  __syncthreads();
  for (int idx = tid; idx < 48 * cV; idx += 256){
    int j = idx / cV, v = idx % cV;
    int o = obase + j;
    float s1 = b1[o], s2 = b2[o];
    #pragma unroll
    for (int c = 0; c < cC; ++c){
      float t = tl[c * cV + v];
      s1 += w1[j * cC + c] * t;
      s2 += w2[j * cC + c] * t;
    }
    g_x1[((size_t)n * cKM + o) * cV + v] = s1;
    g_x2[((size_t)n * cKM + o) * cV + v] = s2;
  }
}

// ---------------------------------------------------------------------------
// 3) ada softmax
// ---------------------------------------------------------------------------
__global__ void gm_ada(const float* __restrict__ beta){
  __shared__ float a1[cMID * cV];
  __shared__ float a2[cMID * cV];
  __shared__ float al[cV * cV];
  int b = blockIdx.x; int n = b / cK, k = b % cK;
  int tid = threadIdx.x;
  const float* p1 = g_x1 + ((size_t)n * cKM + k * cMID) * cV;
  const float* p2 = g_x2 + ((size_t)n * cKM + k * cMID) * cV;
  for (int i = tid; i < cMID * cV; i += 128){ a1[i] = p1[i]; a2[i] = p2[i]; }
  __syncthreads();
  for (int idx = tid; idx < cV * cV; idx += 128){
    int v = idx / cV, w = idx % cV;
    float s = 0.f;
    #pragma unroll
    for (int c = 0; c < cMID; ++c) s += a1[c * cV + v] * a2[c * cV + w];
    al[idx] = s;
  }
  __syncthreads();
  float b0 = beta[0];
  if (tid < cV){
    int w = tid;
    float m = -1e30f;
    for (int v = 0; v < cV; ++v) m = fmaxf(m, al[v * cV + w]);
    float s = 0.f;
    for (int v = 0; v < cV; ++v) s += expf(al[v * cV + w] - m);
    float inv = b0 / s;
    for (int v = 0; v < cV; ++v)
      g_ada[(size_t)b * cV * cV + v * cV + w] = expf(al[v * cV + w] - m) * inv;
  }
}

// ---------------------------------------------------------------------------
// 4+6) MFMA GEMM: C[192 x 64cols] = W[192 x K] @ Z[K x 64cols] per (n, coltile)
//   MODE 0: K=64,  W=g_Wpre,  Z=x (f32->bf16), out = g_pre32 (bf16, relu, PADDED)
//   MODE 1: K=256, W=g_Wcat,  Z=[g_y; x],      out = d_out (f32, relu)
// ---------------------------------------------------------------------------
template<int MODE>
__global__ __launch_bounds__(256) void gm_mm(const float* __restrict__ x,
                                             float* __restrict__ outf){
  constexpr int KTOT = MODE ? 256 : 64;
  constexpr int LDW = 56;
  __shared__ ushort Wt[cKM * LDW];
  __shared__ ushort Zt[64 * LDW];
  __shared__ float cb[cKM];
  int n = blockIdx.x / 25, tile = blockIdx.x % 25;
  int colb = tile * 64;
  int tid = threadIdx.x;
  int lane = tid & 63, wv = tid >> 6;
  int g = lane >> 4, l15 = lane & 15;
  int zr = tid >> 3, cj = (tid & 7) * 8;

  if (tid < cKM) cb[tid] = MODE ? g_cterm[tid] : g_bpre[tid];

  f32x4 acc[3][4];
  #pragma unroll
  for (int a = 0; a < 3; ++a)
    #pragma unroll
    for (int b = 0; b < 4; ++b) acc[a][b] = (f32x4){0.f,0.f,0.f,0.f};

  const ushort* Wsrc = (const ushort*)(MODE ? g_Wcat : g_Wpre);

  for (int kb = 0; kb < KTOT; kb += 32){
    __syncthreads();
    #pragma unroll
    for (int p = 0; p < 3; ++p){
      int c = tid + p * 256;
      int o = c >> 2, kg = (c & 3) * 8;
      uint4 wv4 = *(const uint4*)(Wsrc + o * KTOT + kb + kg);
      *(uint4*)&Wt[o * LDW + kg] = wv4;
    }
    int kt = kb + zr;
    union { uint4 v; ushort u[8]; } zz;
    if (MODE == 1 && kt < cKM){
      zz.v = *(const uint4*)((const ushort*)g_y + ((size_t)n*cKM + kt)*cTV + colb + cj);
    } else {
      int cx = MODE ? (kt - cKM) : kt;
      const float* src = x + ((size_t)n*cC + cx)*cTV + colb + cj;
      float4 f0 = *(const float4*)src;
      float4 f1 = *(const float4*)(src + 4);
      zz.u[0] = f2bu(f0.x); zz.u[1] = f2bu(f0.y);
      zz.u[2] = f2bu(f0.z); zz.u[3] = f2bu(f0.w);
      zz.u[4] = f2bu(f1.x); zz.u[5] = f2bu(f1.y);
      zz.u[6] = f2bu(f1.z); zz.u[7] = f2bu(f1.w);
    }
    #pragma unroll
    for (int j = 0; j < 8; ++j) Zt[(cj + j) * LDW + zr] = zz.u[j];
    __syncthreads();
    s16x8 av[3], bv[4];
    #pragma unroll
    for (int mf = 0; mf < 3; ++mf)
      av[mf] = *(const s16x8*)&Wt[(48*wv + 16*mf + l15) * LDW + 8*g];
    #pragma unroll
    for (int nf = 0; nf < 4; ++nf)
      bv[nf] = *(const s16x8*)&Zt[(16*nf + l15) * LDW + 8*g];
    #pragma unroll
    for (int mf = 0; mf < 3; ++mf)
      #pragma unroll
      for (int nf = 0; nf < 4; ++nf)
        acc[mf][nf] = __builtin_amdgcn_mfma_f32_16x16x32_bf16(av[mf], bv[nf], acc[mf][nf], 0, 0, 0);
  }
  #pragma unroll
  for (int mf = 0; mf < 3; ++mf)
    #pragma unroll
    for (int nf = 0; nf < 4; ++nf)
      #pragma unroll
      for (int q = 0; q < 4; ++q){
        int o = 48*wv + 16*mf + 4*g + q;
        int col = colb + 16*nf + l15;
        float v = fmaxf(acc[mf][nf][q] + cb[o], 0.f);
        if (MODE){
          outf[((size_t)n*cKM + o)*cTV + col] = v;
        } else {
          int t = (col * 5243) >> 17;          // t = col / 25  (col < 1600)
          int vv = col - t * 25;
          g_pre32[(((size_t)n*cKM + o)*cT + t)*32 + vv] = f2bu(v);
        }
      }
}

// ---------------------------------------------------------------------------
// 5) g_y = pre_x @ Adyn via MFMA.  256 thr = 4 waves; wave handles one (n,r).
//    A-frags: direct aligned 16B global loads from padded g_pre32.
//    B-frags: computed in registers (fast tanh); rows v>=25 exact zero.
//    Stores: per-wave LDS repack -> uint4 coalesced global stores.
// ---------------------------------------------------------------------------
__global__ __launch_bounds__(256) void gm_y2(const float* __restrict__ A,
                                             const float* __restrict__ alpha){
  __shared__ ushort yst[4][cT * cV];     // 4 x 3200 B
  int tid = threadIdx.x;
  int wv = tid >> 6, lane = tid & 63, g = lane >> 4, l15 = lane & 15;
  int bid = blockIdx.x;
  int n = bid / 48, r = (bid % 48) * 4 + wv;
  int k = r / cMID;
  float a0 = alpha[0];

  const float* x1p = g_x1 + ((size_t)n * cKM + r) * cV;
  const float* x2p = g_x2 + ((size_t)n * cKM + r) * cV;
  const float* Ak   = A + k * cV * cV;
  const float* adak = g_ada + ((size_t)n * cK + k) * cV * cV;

  float w0 = x2p[l15];
  int w1i = 16 + l15;
  float w1 = (w1i < cV) ? x2p[w1i] : 0.f;

  s16x8 bv0, bv1;
  #pragma unroll
  for (int j = 0; j < 8; ++j){
    int v = 8 * g + j;
    float val0 = 0.f, val1 = 0.f;
    if (v < cV){
      float xv = x1p[v];
      float e0 = __expf(2.f * (xv - w0));
      val0 = __fdividef(e0 - 1.f, e0 + 1.f) * a0 + Ak[v*cV + l15] + adak[v*cV + l15];
      if (w1i < cV){
        float e1 = __expf(2.f * (xv - w1));
        val1 = __fdividef(e1 - 1.f, e1 + 1.f) * a0 + Ak[v*cV + w1i] + adak[v*cV + w1i];
      }
    }
    bv0[j] = (short)f2bu(val0);
    bv1[j] = (short)f2bu(val1);
  }

  const ushort* pb = g_pre32 + ((size_t)n * cKM + r) * cT * 32;
  f32x4 acc[4][2];
  #pragma unroll
  for (int mf = 0; mf < 4; ++mf){
    s16x8 av = *(const s16x8*)(pb + (16*mf + l15) * 32 + 8*g);
    acc[mf][0] = __builtin_amdgcn_mfma_f32_16x16x32_bf16(av, bv0, (f32x4){0.f,0.f,0.f,0.f}, 0, 0, 0);
    acc[mf][1] = __builtin_amdgcn_mfma_f32_16x16x32_bf16(av, bv1, (f32x4){0.f,0.f,0.f,0.f}, 0, 0, 0);
  }

  // repack D -> LDS (compact [t][25]); 2B writes, <=2-way word aliasing (free)
  #pragma unroll
  for (int mf = 0; mf < 4; ++mf)
    #pragma unroll
    for (int nf = 0; nf < 2; ++nf)
      #pragma unroll
      for (int q = 0; q < 4; ++q){
        int t = 16*mf + 4*g + q, w = 16*nf + l15;
        if (w < cV) yst[wv][t * cV + w] = f2bu(acc[mf][nf][q]);
      }
  __syncthreads();
  // coalesced copy-out: 3200 B per wave = 200 uint4
  const uint4* src = (const uint4*)yst[wv];
  uint4* dst = (uint4*)((ushort*)g_y + ((size_t)n * cKM + r) * cTV);
  #pragma unroll
  for (int i = 0; i < 3; ++i) dst[lane + 64*i] = src[lane + 64*i];
  if (lane < 8) dst[lane + 192] = src[lane + 192];
}

// ---------------------------------------------------------------------------
extern "C" void kernel_launch(void* const* d_in, const int* in_sizes, int n_in,
                              void* d_out, int out_size, void* d_ws, size_t ws_size,
                              hipStream_t stream){
  (void)in_sizes; (void)n_in; (void)out_size; (void)d_ws; (void)ws_size;
  const float* x      = (const float*)d_in[0];
  const float* A      = (const float*)d_in[1];
  const float* alpha  = (const float*)d_in[2];
  const float* beta   = (const float*)d_in[3];
  const float* W_pre  = (const float*)d_in[4];
  const float* b_pre  = (const float*)d_in[5];
  const float* bn_pre = (const float*)d_in[6];
  const float* W1     = (const float*)d_in[7];
  const float* b1     = (const float*)d_in[8];
  const float* W2     = (const float*)d_in[9];
  const float* b2     = (const float*)d_in[10];
  const float* W_post = (const float*)d_in[11];
  const float* b_post = (const float*)d_in[12];
  const float* bn_post= (const float*)d_in[13];
  const float* W_down = (const float*)d_in[14];
  const float* b_down = (const float*)d_in[15];
  const float* bn_down= (const float*)d_in[16];
  float* out = (float*)d_out;

  k_fold  <<<1,         256, 0, stream>>>(W_pre, b_pre, bn_pre,
                                          W_post, b_post, bn_post,
                                          W_down, b_down, bn_down);
  gm_tmp  <<<cN * cC,    64, 0, stream>>>(x);
  gm_x1x2 <<<cN * 4,    256, 0, stream>>>(W1, b1, W2, b2);
  gm_ada  <<<cN * cK,   128, 0, stream>>>(beta);
  gm_mm<0><<<cN * 25,   256, 0, stream>>>(x, nullptr);
  gm_y2   <<<cN * 48,   256, 0, stream>>>(A, alpha);
  gm_mm<1><<<cN * 25,   256, 0, stream>>>(x, out);
}